// Round 5
// baseline (8647.456 us; speedup 1.0000x reference)
//
#include <hip/hip_runtime.h>

// Seq2Seq LSTM (B=2048, T=100, E=512, FUTURE=10, POSE=34). FP32 in/out.
// bf16 MFMA, SPLIT WEIGHTS (W = W_hi + W_lo bf16 planes, K=1024 as 16 chunks),
// h-state bf16, c-state fp32.
// R4: NO LDS, NO BARRIERS. Weights pre-swizzled into B-fragment streaming
// order -> coalesced global_load_dwordx4 direct to VGPR b-frags. A-frags
// gathered per-lane (16 rows x 64B segments = minimum cacheline count).
// K-loop = register-double-buffered load/MFMA interleave (AITER-style,
// compiler-managed vmcnt). E0 pinned to XCD via blockIdx&7 so each XCD's
// 1 MB weight slice stays L2-resident across all 100 timesteps.
// Block = 256 thr (4 waves) = 1 block/CU; tile 64 rows x 64 e-cols x 4 gates;
// i,f,g,o of one (b,e) share a lane/register -> per-lane pointwise epilogue.

#define TSEQ 100
#define FUT 10
#define POSE_D 34
#define EDIM 512
#define BDIM 2048

typedef __bf16 bf16x8 __attribute__((ext_vector_type(8)));
typedef float floatx4 __attribute__((ext_vector_type(4)));
typedef short shortx8 __attribute__((ext_vector_type(8)));

__device__ __forceinline__ float bf2f(short s) {
    unsigned int u = ((unsigned int)(unsigned short)s) << 16;
    float f;
    __builtin_memcpy(&f, &u, 4);
    return f;
}
__device__ __forceinline__ short f2bf(float f) {
    unsigned int u;
    __builtin_memcpy(&u, &f, 4);
    u += 0x7fffu + ((u >> 16) & 1u);
    return (short)(u >> 16);
}
__device__ __forceinline__ __bf16 f2bf16(float f) {
    short s = f2bf(f);
    __bf16 b;
    __builtin_memcpy(&b, &s, 2);
    return b;
}
__device__ __forceinline__ float fsig(float x) { return 1.f / (1.f + __expf(-x)); }
__device__ __forceinline__ float ftanh(float x) {
    float ax = fabsf(x);
    float t = __expf(-2.f * ax);
    float r = (1.f - t) / (1.f + t);
    return x < 0.f ? -r : r;
}

// Swizzled W layout, in 1KB "wave units" of 64 lanes x 16B:
//   unit(e0,kc,w,g,kk) = (((e0*NW + kc)*4 + w)*4 + g)*2 + kk   (NW = chunks)
//   shorts addr = unit*512 + lane*8
//   source: row = g*512 + e0*64 + w*16 + (lane&15),
//           k   = (kc&7)*64 + kk*32 + (lane>>4)*8  (plane: kc<8 hi, else lo)

template <bool HAS_X, bool TWO_H>
__global__ __launch_bounds__(256, 1) void lstm_cell_kernel(
    const float* __restrict__ xptr, const short* __restrict__ M1,
    const short* __restrict__ A1, const short* __restrict__ W1,
    const short* __restrict__ A2, const short* __restrict__ W2,
    const float* __restrict__ bias, float* __restrict__ c_io,
    short* __restrict__ h_out, float* __restrict__ hf_out) {
    const int tid = threadIdx.x;
    const int lane = tid & 63;
    const int wv = tid >> 6;
    const int m = lane & 15;
    const int q = lane >> 4;
    const int e0 = blockIdx.x & 7;
    const int R0 = (blockIdx.x >> 3) * 64;
    const int E0 = e0 * 64;

    constexpr int NCH0 = HAS_X ? 1 : 16;          // phase-0 chunks (x or h)
    constexpr int NT = NCH0 + ((HAS_X || TWO_H) ? 16 : 0);

    floatx4 acc[4][4];
#pragma unroll
    for (int ri = 0; ri < 4; ++ri)
#pragma unroll
        for (int g = 0; g < 4; ++g) acc[ri][g] = {0.f, 0.f, 0.f, 0.f};

    // Per-ri row base pointers (kc-invariant), for each phase's A.
    const short* baseA1[4];
    const short* baseA2[4];
#pragma unroll
    for (int ri = 0; ri < 4; ++ri) {
        const int row = R0 + ri * 16 + m;
        baseA1[ri] = A1 ? A1 + (long)row * EDIM + q * 8 : nullptr;
        baseA2[ri] = A2 ? A2 + (long)row * EDIM + q * 8 : nullptr;
    }
    const float* basex[4];
    if (HAS_X) {
#pragma unroll
        for (int ri = 0; ri < 4; ++ri)
            basex[ri] = xptr + (long)(R0 + ri * 16 + m) * (TSEQ * POSE_D) + q * 8;
    }

    bf16x8 rA0[8], rW0[8], rA1[8], rW1[8];

    auto loadc = [&](int kc, bf16x8(&a)[8], bf16x8(&w_)[8]) {
        if (HAS_X && kc == 0) {
            // --- x-chunk: K=64 padded from 34 fp32 cols ---
            const long wb = ((long)(e0 * 4 + wv) * 8) * 512;  // NW=1, kcp=0
#pragma unroll
            for (int gk = 0; gk < 8; ++gk)
                w_[gk] = *(const bf16x8*)(M1 + wb + gk * 512 + lane * 8);
#pragma unroll
            for (int ri = 0; ri < 4; ++ri) {
                // kk=0: k = q*8+j in [0,32) -> always valid
                bf16x8 v0;
#pragma unroll
                for (int j = 0; j < 8; ++j) v0[j] = f2bf16(basex[ri][j]);
                a[ri * 2] = v0;
                // kk=1: k = 32+q*8+j -> valid only q==0, j<2
                bf16x8 v1 = {};
                if (q == 0) {
                    v1[0] = f2bf16(basex[ri][32]);
                    v1[1] = f2bf16(basex[ri][33]);
                }
                a[ri * 2 + 1] = v1;
            }
            return;
        }
        const short* const* bA;
        const short* W;
        int kcp;
        if (TWO_H && kc >= 16) {
            bA = baseA2; W = W2; kcp = kc - 16;
        } else if (HAS_X) {
            bA = baseA2; W = W2; kcp = kc - 1;
        } else {
            bA = baseA1; W = W1; kcp = kc;
        }
        const int k0 = (kcp & 7) * 64;  // A K=512 re-read for hi & lo planes
        const long wb = ((long)((e0 * 16 + kcp) * 4 + wv) * 8) * 512;
#pragma unroll
        for (int gk = 0; gk < 8; ++gk)
            w_[gk] = *(const bf16x8*)(W + wb + gk * 512 + lane * 8);
#pragma unroll
        for (int ri = 0; ri < 4; ++ri) {
            a[ri * 2] = *(const bf16x8*)(bA[ri] + k0);
            a[ri * 2 + 1] = *(const bf16x8*)(bA[ri] + k0 + 32);
        }
    };
    auto domfma = [&](bf16x8(&a)[8], bf16x8(&w_)[8]) {
#pragma unroll
        for (int kk = 0; kk < 2; ++kk)
#pragma unroll
            for (int ri = 0; ri < 4; ++ri)
#pragma unroll
                for (int g = 0; g < 4; ++g)
                    acc[ri][g] = __builtin_amdgcn_mfma_f32_16x16x32_bf16(
                        a[ri * 2 + kk], w_[g * 2 + kk], acc[ri][g], 0, 0, 0);
    };

    loadc(0, rA0, rW0);
#pragma unroll 1
    for (int kc = 0; kc + 1 < NT; kc += 2) {
        loadc(kc + 1, rA1, rW1);
        domfma(rA0, rW0);
        if (kc + 2 < NT) loadc(kc + 2, rA0, rW0);
        domfma(rA1, rW1);
    }
    if (NT & 1) domfma(rA0, rW0);

    // ---- fused LSTM pointwise epilogue (per-lane: i,f,g,o share lane/reg) ----
    const int e = E0 + wv * 16 + m;
    const float bi = bias[e];
    const float bfv = bias[512 + e];
    const float bg = bias[1024 + e];
    const float bo = bias[1536 + e];
#pragma unroll
    for (int ri = 0; ri < 4; ++ri) {
#pragma unroll
        for (int rg = 0; rg < 4; ++rg) {
            const int br = R0 + ri * 16 + q * 4 + rg;  // C/D: row=q*4+reg, col=lane&15
            const long cidx = (long)br * EDIM + e;
            const float iv = fsig(acc[ri][0][rg] + bi);
            const float fv = fsig(acc[ri][1][rg] + bfv);
            const float gv = ftanh(acc[ri][2][rg] + bg);
            const float ov = fsig(acc[ri][3][rg] + bo);
            const float cn = fv * c_io[cidx] + iv * gv;
            c_io[cidx] = cn;
            const float hv = ov * ftanh(cn);
            h_out[cidx] = f2bf(hv);
            if (hf_out) hf_out[cidx] = hv;
        }
    }
}

__global__ __launch_bounds__(256) void zero_kernel(unsigned int* __restrict__ p, int n) {
    int i = blockIdx.x * 256 + threadIdx.x;
    const int stride = gridDim.x * 256;
    for (; i < n; i += stride) p[i] = 0u;
}

// bias1 = bih1 + bhh1 + Wih1 @ enc_lin_b ; bias2 = bih2+bhh2 ; biasd = dbih+dbhh
__global__ __launch_bounds__(256) void prep_bias(
    const float* __restrict__ bih1, const float* __restrict__ bhh1,
    const float* __restrict__ Wih1, const float* __restrict__ encb,
    const float* __restrict__ bih2, const float* __restrict__ bhh2,
    const float* __restrict__ dbih, const float* __restrict__ dbhh,
    float* __restrict__ bias1, float* __restrict__ bias2, float* __restrict__ biasd) {
    const int n = blockIdx.x * 256 + threadIdx.x;
    if (n >= 2048) return;
    float s = bih1[n] + bhh1[n];
    const float* wr = Wih1 + (long)n * EDIM;
    for (int j = 0; j < EDIM; ++j) s += wr[j] * encb[j];
    bias1[n] = s;
    bias2[n] = bih2[n] + bhh2[n];
    biasd[n] = dbih[n] + dbhh[n];
}

// Swizzle fp32 W[2048x512] (+optional addend) into hi|lo bf16 frag-stream
// order: 262144 units of 8 shorts; idx bits e0[17:15] kc[14:11] w[10:9]
// g[8:7] kk[6] lane[5:0].
__global__ __launch_bounds__(256) void swizzle_w(const float* __restrict__ a,
                                                 const float* __restrict__ b,
                                                 short* __restrict__ o) {
    const int idx = blockIdx.x * 256 + threadIdx.x;
    if (idx >= 262144) return;
    const int lane = idx & 63, kk = (idx >> 6) & 1, g = (idx >> 7) & 3;
    const int w = (idx >> 9) & 3, kc = (idx >> 11) & 15, e0 = idx >> 15;
    const int row = g * 512 + e0 * 64 + w * 16 + (lane & 15);
    const int ks = (kc & 7) * 64 + kk * 32 + (lane >> 4) * 8;
    const bool lo = kc >= 8;
    shortx8 outv;
#pragma unroll
    for (int j = 0; j < 8; ++j) {
        const long si = (long)row * EDIM + ks + j;
        const float v = b ? (a[si] + b[si]) : a[si];
        const short hi = f2bf(v);
        outv[j] = lo ? f2bf(v - bf2f(hi)) : hi;
    }
    *(shortx8*)(o + (long)idx * 8) = outv;
}

// M1 = Wih1 @ enc_lin_W (K padded 34->64), swizzled (NW=1): 16384 units;
// idx bits e0[13:11] w[10:9] g[8:7] kk[6] lane[5:0].
__global__ __launch_bounds__(256) void swizzle_M1(const float* __restrict__ Wih1,
                                                  const float* __restrict__ encW,
                                                  short* __restrict__ o) {
    const int idx = blockIdx.x * 256 + threadIdx.x;
    if (idx >= 16384) return;
    const int lane = idx & 63, kk = (idx >> 6) & 1, g = (idx >> 7) & 3;
    const int w = (idx >> 9) & 3, e0 = idx >> 11;
    const int row = g * 512 + e0 * 64 + w * 16 + (lane & 15);
    const int ks = kk * 32 + (lane >> 4) * 8;
    shortx8 outv;
#pragma unroll
    for (int j = 0; j < 8; ++j) {
        const int k = ks + j;
        float s = 0.f;
        if (k < POSE_D) {
            const float* wr = Wih1 + (long)row * EDIM;
            for (int jj = 0; jj < EDIM; ++jj) s += wr[jj] * encW[jj * POSE_D + k];
        }
        outv[j] = f2bf(s);
    }
    *(shortx8*)(o + (long)idx * 8) = outv;
}

// out[b,f,p] = hf[b,:] . dec_lin_W[p,:] + dec_lin_b[p]  (pure fp32)
__global__ __launch_bounds__(64) void out_proj(const float* __restrict__ hf,
                                               const float* __restrict__ W,
                                               const float* __restrict__ bias,
                                               float* __restrict__ out, int f) {
    const int b = blockIdx.x;
    __shared__ float hrow[EDIM];
    const int lane = threadIdx.x;
    *(floatx4*)(hrow + lane * 8) = *(const floatx4*)(hf + (long)b * EDIM + lane * 8);
    *(floatx4*)(hrow + lane * 8 + 4) = *(const floatx4*)(hf + (long)b * EDIM + lane * 8 + 4);
    __syncthreads();
    if (lane < POSE_D) {
        float acc = bias[lane];
        const float* wr = W + (long)lane * EDIM;
        for (int e = 0; e < EDIM; e += 4) {
            const floatx4 wv = *(const floatx4*)(wr + e);
            acc += hrow[e] * wv[0] + hrow[e + 1] * wv[1] + hrow[e + 2] * wv[2] + hrow[e + 3] * wv[3];
        }
        out[((long)b * FUT + f) * POSE_D + lane] = acc;
    }
}

extern "C" void kernel_launch(void* const* d_in, const int* in_sizes, int n_in,
                              void* d_out, int out_size, void* d_ws, size_t ws_size,
                              hipStream_t stream) {
    const float* x = (const float*)d_in[0];
    const float* encW = (const float*)d_in[1];
    const float* encb = (const float*)d_in[2];
    const float* Wih1 = (const float*)d_in[3];
    const float* Whh1 = (const float*)d_in[4];
    const float* bih1 = (const float*)d_in[5];
    const float* bhh1 = (const float*)d_in[6];
    const float* Wih2 = (const float*)d_in[7];
    const float* Whh2 = (const float*)d_in[8];
    const float* bih2 = (const float*)d_in[9];
    const float* bhh2 = (const float*)d_in[10];
    const float* dWih = (const float*)d_in[11];
    const float* dWhh = (const float*)d_in[12];
    const float* dbih = (const float*)d_in[13];
    const float* dbhh = (const float*)d_in[14];
    const float* oW = (const float*)d_in[15];
    const float* ob = (const float*)d_in[16];
    float* out = (float*)d_out;

    char* ws = (char*)d_ws;
    size_t off = 0;
    auto alloc = [&](size_t bytes) -> char* {
        char* p = ws + off;
        off = (off + bytes + 255) & ~(size_t)255;
        return p;
    };
    const size_t HB = (size_t)BDIM * EDIM * 2;   // 2 MB bf16 state
    const size_t CB = (size_t)BDIM * EDIM * 4;   // 4 MB fp32 state
    const size_t WSZ = (size_t)262144 * 16;      // 4 MB swizzled split-W
    // zero-region (contiguous): h1_0, h2_0, c1, c2
    short* h1_0 = (short*)alloc(HB);
    short* h2_0 = (short*)alloc(HB);
    float* c1 = (float*)alloc(CB);
    float* c2 = (float*)alloc(CB);
    short* h1_1 = (short*)alloc(HB);
    short* h2_1 = (short*)alloc(HB);
    float* hf0 = (float*)alloc(CB);
    float* hf1 = (float*)alloc(CB);
    short* M1 = (short*)alloc((size_t)16384 * 16);
    short* sWhh1 = (short*)alloc(WSZ);
    short* sWih2 = (short*)alloc(WSZ);
    short* sWhh2 = (short*)alloc(WSZ);
    short* sdWhh = (short*)alloc(WSZ);
    short* sWsum = (short*)alloc(WSZ);
    float* bias1 = (float*)alloc(2048 * 4);
    float* bias2 = (float*)alloc(2048 * 4);
    float* biasd = (float*)alloc(2048 * 4);
    (void)ws_size; (void)in_sizes; (void)n_in; (void)out_size;

    zero_kernel<<<2048, 256, 0, stream>>>((unsigned int*)h1_0, (int)((2 * HB + 2 * CB) / 4));
    prep_bias<<<8, 256, 0, stream>>>(bih1, bhh1, Wih1, encb, bih2, bhh2, dbih, dbhh,
                                     bias1, bias2, biasd);
    swizzle_M1<<<64, 256, 0, stream>>>(Wih1, encW, M1);
    swizzle_w<<<1024, 256, 0, stream>>>(Whh1, nullptr, sWhh1);
    swizzle_w<<<1024, 256, 0, stream>>>(Wih2, nullptr, sWih2);
    swizzle_w<<<1024, 256, 0, stream>>>(Whh2, nullptr, sWhh2);
    swizzle_w<<<1024, 256, 0, stream>>>(dWhh, nullptr, sdWhh);
    swizzle_w<<<1024, 256, 0, stream>>>(dWih, dWhh, sWsum);

    dim3 grid(256), blk(256);
    short *h1p = h1_0, *h1n = h1_1, *h2p = h2_0, *h2n = h2_1;
    for (int t = 0; t < TSEQ; ++t) {
        lstm_cell_kernel<true, false><<<grid, blk, 0, stream>>>(
            x + t * POSE_D, M1, nullptr, nullptr, h1p, sWhh1,
            bias1, c1, h1n, nullptr);
        lstm_cell_kernel<false, true><<<grid, blk, 0, stream>>>(
            nullptr, nullptr, h1n, sWih2, h2p, sWhh2,
            bias2, c2, h2n, nullptr);
        short* t1 = h1p; h1p = h1n; h1n = t1;
        short* t2 = h2p; h2p = h2n; h2n = t2;
    }
    // decoder: bf16 h ping-pong reuses freed h1 buffers; fp32 copy for out_proj
    short* hd0 = h1_1;
    short* hd1 = h1_0;
    lstm_cell_kernel<false, false><<<grid, blk, 0, stream>>>(
        nullptr, nullptr, h2p, sdWhh, nullptr, nullptr,
        biasd, c2, hd0, hf0);
    out_proj<<<BDIM, 64, 0, stream>>>(hf0, oW, ob, out, 0);
    short *dp = hd0, *dn = hd1;
    float *fp = hf0, *fn = hf1;
    for (int f = 1; f < FUT; ++f) {
        lstm_cell_kernel<false, false><<<grid, blk, 0, stream>>>(
            nullptr, nullptr, dp, sWsum, nullptr, nullptr,
            biasd, c2, dn, fn);
        out_proj<<<BDIM, 64, 0, stream>>>(fn, oW, ob, out, f);
        short* tt = dp; dp = dn; dn = tt;
        float* tf = fp; fp = fn; fn = tf;
    }
}

// Round 6
// 5372.018 us; speedup vs baseline: 1.6097x; 1.6097x over previous
//
#include <hip/hip_runtime.h>

// Seq2Seq LSTM (B=2048, T=100, E=512, FUTURE=10, POSE=34). FP32 in/out.
// bf16 MFMA, SPLIT WEIGHTS (W = W_hi + W_lo bf16, K=1024/phase), h bf16,
// c fp32. R5 structure:
//  - 256 blocks x 512 threads (8 waves/CU = 2/SIMD). wave=(es e-subset, kg).
//  - A panels (64 rows x K512) staged to LDS ONCE per phase, XOR-swizzled;
//    K-loop has NO internal barriers.
//  - W streamed direct global->VGPR from pre-swizzled layout (coalesced 1KB
//    insts, zero redundancy), register ping-pong prefetch 1 chunk ahead.
//  - kg groups take alternate 64-K chunks; partials reduced via LDS once.
//  - e0 = blockIdx&7 XCD-pins each 64-e weight slice L2-resident.
// Epilogue: i,f,g,o of one (b,e) share a lane/register -> per-lane LSTM.

#define TSEQ 100
#define FUT 10
#define POSE_D 34
#define EDIM 512
#define BDIM 2048

typedef __bf16 bf16x8 __attribute__((ext_vector_type(8)));
typedef float floatx4 __attribute__((ext_vector_type(4)));
typedef short shortx8 __attribute__((ext_vector_type(8)));

__device__ __forceinline__ float bf2f(short s) {
    unsigned int u = ((unsigned int)(unsigned short)s) << 16;
    float f;
    __builtin_memcpy(&f, &u, 4);
    return f;
}
__device__ __forceinline__ short f2bf(float f) {
    unsigned int u;
    __builtin_memcpy(&u, &f, 4);
    u += 0x7fffu + ((u >> 16) & 1u);
    return (short)(u >> 16);
}
__device__ __forceinline__ float fsig(float x) { return 1.f / (1.f + __expf(-x)); }
__device__ __forceinline__ float ftanh(float x) {
    float ax = fabsf(x);
    float t = __expf(-2.f * ax);
    float r = (1.f - t) / (1.f + t);
    return x < 0.f ? -r : r;
}

// Swizzled W stream layout (1KB wave units):
//   unit(e0,kcp,es,g,kk) = (((e0*16 + kcp)*4 + es)*4 + g)*2 + kk ; shorts = unit*512 + lane*8
//   source row = g*512 + e0*64 + es*16 + (lane&15), k = (kcp&7)*64 + kk*32 + (lane>>4)*8
//   plane: kcp<8 -> hi, kcp>=8 -> lo.   M1 uses the same with NW=1 (kcp=0).

template <bool HAS_X, bool TWO_H>
__global__ __launch_bounds__(512, 2) void lstm_cell_kernel(
    const float* __restrict__ xptr, const short* __restrict__ M1,
    const short* __restrict__ A1, const short* __restrict__ W1,
    const short* __restrict__ A2, const short* __restrict__ W2,
    const float* __restrict__ bias, float* __restrict__ c_io,
    short* __restrict__ h_out, float* __restrict__ hf_out) {
    __shared__ __align__(16) short lds[65536];  // 128 KB
    const int tid = threadIdx.x;
    const int lane = tid & 63;
    const int wv = tid >> 6;
    const int es = wv & 3;
    const int kg = wv >> 2;
    const int m = lane & 15;
    const int q = lane >> 4;
    const int e0 = blockIdx.x & 7;
    const int R0 = (blockIdx.x >> 3) * 64;
    const int E0 = e0 * 64;

    constexpr int NT = HAS_X ? 17 : (TWO_H ? 32 : 16);
    constexpr int AOFF1 = HAS_X ? 4096 : 0;  // shorts
    constexpr int AOFF2 = 32768;

    floatx4 acc[4][4];
#pragma unroll
    for (int ri = 0; ri < 4; ++ri)
#pragma unroll
        for (int g = 0; g < 4; ++g) acc[ri][g] = {0.f, 0.f, 0.f, 0.f};

    bf16x8 rW0[8], rW1[8];

    auto loadW = [&](int c, bf16x8(&w_)[8]) {
        const short* P;
        if (HAS_X && c == 0) {
            P = M1 + (long)((e0 * 4 + es) * 8) * 512 + lane * 8;
        } else {
            const short* W;
            int kcp;
            if (HAS_X) { W = W1; kcp = c - 1; }
            else if (TWO_H) { W = (c < 16) ? W1 : W2; kcp = (c < 16) ? c : c - 16; }
            else { W = W1; kcp = c; }
            P = W + (long)((e0 * 16 + kcp) * 4 + es) * 4096 + lane * 8;
        }
#pragma unroll
        for (int i = 0; i < 8; ++i) w_[i] = *(const bf16x8*)(P + i * 512);
    };

    auto do_chunk = [&](int c, bf16x8(&w_)[8]) {
        if (HAS_X && c == 0) {  // x-chunk (rows of 8 units)
#pragma unroll
            for (int kk = 0; kk < 2; ++kk) {
                bf16x8 a[4];
#pragma unroll
                for (int ri = 0; ri < 4; ++ri) {
                    const int row = ri * 16 + m;
                    a[ri] = *(const bf16x8*)(lds + row * 64 + (((kk * 4 + q) ^ (row & 7)) << 3));
                }
#pragma unroll
                for (int ri = 0; ri < 4; ++ri)
#pragma unroll
                    for (int g = 0; g < 4; ++g)
                        acc[ri][g] = __builtin_amdgcn_mfma_f32_16x16x32_bf16(
                            a[ri], w_[g * 2 + kk], acc[ri][g], 0, 0, 0);
            }
            return;
        }
        int aoff, kcp;
        if (HAS_X) { aoff = AOFF1; kcp = c - 1; }
        else if (TWO_H) { aoff = (c < 16) ? 0 : AOFF2; kcp = (c < 16) ? c : c - 16; }
        else { aoff = 0; kcp = c; }
        const int k8 = (kcp & 7) * 8;
#pragma unroll
        for (int kk = 0; kk < 2; ++kk) {
            bf16x8 a[4];
#pragma unroll
            for (int ri = 0; ri < 4; ++ri) {
                const int row = ri * 16 + m;
                a[ri] = *(const bf16x8*)(lds + aoff + row * 512 +
                                         ((k8 | (((kk * 4 + q) ^ row) & 7)) << 3));
            }
#pragma unroll
            for (int ri = 0; ri < 4; ++ri)
#pragma unroll
                for (int g = 0; g < 4; ++g)
                    acc[ri][g] = __builtin_amdgcn_mfma_f32_16x16x32_bf16(
                        a[ri], w_[g * 2 + kk], acc[ri][g], 0, 0, 0);
        }
    };

    // Stage a 64-row x 512-K bf16 panel into LDS (XOR-swizzled 16B units).
    auto stageA = [&](const short* __restrict__ G, int dst) {
#pragma unroll
        for (int i = 0; i < 8; ++i) {
            const int u = tid + (i << 9);
            const int r = u >> 6, c = u & 63;
            const shortx8 v = *(const shortx8*)(G + (long)r * 512 + (c << 3));
            *(shortx8*)(lds + dst + r * 512 + (((c & 56) | ((c ^ r) & 7)) << 3)) = v;
        }
    };

    loadW(kg, rW0);  // first chunk's W in flight during staging

    if (HAS_X) {
        floatx4 z = {0.f, 0.f, 0.f, 0.f};
        *(floatx4*)(lds + tid * 8) = z;  // zero x-area (4096 shorts)
        stageA(A1 + (long)R0 * 512, AOFF1);
        __syncthreads();  // zero-fill visible before scalar x overwrite
        for (int idx = tid; idx < 64 * POSE_D; idx += 512) {
            const int r = idx / POSE_D;
            const int c = idx - r * POSE_D;
            lds[r * 64 + (((c >> 3) ^ (r & 7)) << 3) + (c & 7)] =
                f2bf(xptr[(long)(R0 + r) * (TSEQ * POSE_D) + c]);
        }
    } else {
        stageA(A1 + (long)R0 * 512, 0);
        if (TWO_H) stageA(A2 + (long)R0 * 512, AOFF2);
    }
    __syncthreads();

    // ---- barrier-free K-loop: W reg ping-pong, A from LDS ----
    int c = kg;
#pragma unroll 1
    while (true) {
        if (c + 2 < NT) loadW(c + 2, rW1);
        do_chunk(c, rW0);
        c += 2;
        if (c >= NT) break;
        if (c + 2 < NT) loadW(c + 2, rW0);
        do_chunk(c, rW1);
        c += 2;
        if (c >= NT) break;
    }

    // ---- cross-kg reduction via LDS (stride 68 floats + XOR, ~conflict-free) ----
    __syncthreads();
    float* ldsf = (float*)lds;
    const int L = es * 64 + lane;
    if (kg == 1) {
#pragma unroll
        for (int ri = 0; ri < 4; ++ri)
#pragma unroll
            for (int g = 0; g < 4; ++g) {
                const int f4 = ri * 4 + g;
                *(floatx4*)(ldsf + L * 68 + ((f4 ^ (lane & 15)) << 2)) = acc[ri][g];
            }
    }
    __syncthreads();
    if (kg == 0) {
#pragma unroll
        for (int ri = 0; ri < 4; ++ri)
#pragma unroll
            for (int g = 0; g < 4; ++g) {
                const int f4 = ri * 4 + g;
                acc[ri][g] += *(const floatx4*)(ldsf + L * 68 + ((f4 ^ (lane & 15)) << 2));
            }
        // ---- fused LSTM pointwise epilogue (per-lane i,f,g,o) ----
        const int e = E0 + es * 16 + m;
        const float bi = bias[e];
        const float bfv = bias[512 + e];
        const float bg = bias[1024 + e];
        const float bo = bias[1536 + e];
#pragma unroll
        for (int ri = 0; ri < 4; ++ri) {
#pragma unroll
            for (int rg = 0; rg < 4; ++rg) {
                const int br = R0 + ri * 16 + q * 4 + rg;  // C/D: row=q*4+reg, col=lane&15
                const long cidx = (long)br * EDIM + e;
                const float iv = fsig(acc[ri][0][rg] + bi);
                const float fv = fsig(acc[ri][1][rg] + bfv);
                const float gv = ftanh(acc[ri][2][rg] + bg);
                const float ov = fsig(acc[ri][3][rg] + bo);
                const float cn = fv * c_io[cidx] + iv * gv;
                c_io[cidx] = cn;
                const float hv = ov * ftanh(cn);
                h_out[cidx] = f2bf(hv);
                if (hf_out) hf_out[cidx] = hv;
            }
        }
    }
}

__global__ __launch_bounds__(256) void zero_kernel(unsigned int* __restrict__ p, int n) {
    int i = blockIdx.x * 256 + threadIdx.x;
    const int stride = gridDim.x * 256;
    for (; i < n; i += stride) p[i] = 0u;
}

// bias1 = bih1 + bhh1 + Wih1 @ enc_lin_b ; bias2 = bih2+bhh2 ; biasd = dbih+dbhh
__global__ __launch_bounds__(256) void prep_bias(
    const float* __restrict__ bih1, const float* __restrict__ bhh1,
    const float* __restrict__ Wih1, const float* __restrict__ encb,
    const float* __restrict__ bih2, const float* __restrict__ bhh2,
    const float* __restrict__ dbih, const float* __restrict__ dbhh,
    float* __restrict__ bias1, float* __restrict__ bias2, float* __restrict__ biasd) {
    const int n = blockIdx.x * 256 + threadIdx.x;
    if (n >= 2048) return;
    float s = bih1[n] + bhh1[n];
    const float* wr = Wih1 + (long)n * EDIM;
    for (int j = 0; j < EDIM; ++j) s += wr[j] * encb[j];
    bias1[n] = s;
    bias2[n] = bih2[n] + bhh2[n];
    biasd[n] = dbih[n] + dbhh[n];
}

// Swizzle fp32 W[2048x512] (+optional addend) into hi|lo bf16 frag-stream.
__global__ __launch_bounds__(256) void swizzle_w(const float* __restrict__ a,
                                                 const float* __restrict__ b,
                                                 short* __restrict__ o) {
    const int idx = blockIdx.x * 256 + threadIdx.x;
    if (idx >= 262144) return;
    const int lane = idx & 63, kk = (idx >> 6) & 1, g = (idx >> 7) & 3;
    const int w = (idx >> 9) & 3, kc = (idx >> 11) & 15, e0 = idx >> 15;
    const int row = g * 512 + e0 * 64 + w * 16 + (lane & 15);
    const int ks = (kc & 7) * 64 + kk * 32 + (lane >> 4) * 8;
    const bool lo = kc >= 8;
    shortx8 outv;
#pragma unroll
    for (int j = 0; j < 8; ++j) {
        const long si = (long)row * EDIM + ks + j;
        const float v = b ? (a[si] + b[si]) : a[si];
        const short hi = f2bf(v);
        outv[j] = lo ? f2bf(v - bf2f(hi)) : hi;
    }
    *(shortx8*)(o + (long)idx * 8) = outv;
}

// M1 = Wih1 @ enc_lin_W (K pad 34->64), swizzled, one thread per element.
__global__ __launch_bounds__(256) void swizzle_M1(const float* __restrict__ Wih1,
                                                  const float* __restrict__ encW,
                                                  short* __restrict__ o) {
    const int idx = blockIdx.x * 256 + threadIdx.x;
    if (idx >= 131072) return;
    const int u = idx >> 3, j = idx & 7;
    const int lane = u & 63, kk = (u >> 6) & 1, g = (u >> 7) & 3;
    const int w = (u >> 9) & 3, e0 = u >> 11;
    const int row = g * 512 + e0 * 64 + w * 16 + (lane & 15);
    const int k = kk * 32 + (lane >> 4) * 8 + j;
    float s = 0.f;
    if (k < POSE_D) {
        const float* wr = Wih1 + (long)row * EDIM;
        for (int jj = 0; jj < EDIM; ++jj) s += wr[jj] * encW[jj * POSE_D + k];
    }
    o[(long)u * 8 + j] = f2bf(s);
}

// out[b,f,p] = hf[b,:] . dec_lin_W[p,:] + dec_lin_b[p]  (pure fp32)
__global__ __launch_bounds__(64) void out_proj(const float* __restrict__ hf,
                                               const float* __restrict__ W,
                                               const float* __restrict__ bias,
                                               float* __restrict__ out, int f) {
    const int b = blockIdx.x;
    __shared__ float hrow[EDIM];
    const int lane = threadIdx.x;
    *(floatx4*)(hrow + lane * 8) = *(const floatx4*)(hf + (long)b * EDIM + lane * 8);
    *(floatx4*)(hrow + lane * 8 + 4) = *(const floatx4*)(hf + (long)b * EDIM + lane * 8 + 4);
    __syncthreads();
    if (lane < POSE_D) {
        float acc = bias[lane];
        const float* wr = W + (long)lane * EDIM;
        for (int e = 0; e < EDIM; e += 4) {
            const floatx4 wv = *(const floatx4*)(wr + e);
            acc += hrow[e] * wv[0] + hrow[e + 1] * wv[1] + hrow[e + 2] * wv[2] + hrow[e + 3] * wv[3];
        }
        out[((long)b * FUT + f) * POSE_D + lane] = acc;
    }
}

extern "C" void kernel_launch(void* const* d_in, const int* in_sizes, int n_in,
                              void* d_out, int out_size, void* d_ws, size_t ws_size,
                              hipStream_t stream) {
    const float* x = (const float*)d_in[0];
    const float* encW = (const float*)d_in[1];
    const float* encb = (const float*)d_in[2];
    const float* Wih1 = (const float*)d_in[3];
    const float* Whh1 = (const float*)d_in[4];
    const float* bih1 = (const float*)d_in[5];
    const float* bhh1 = (const float*)d_in[6];
    const float* Wih2 = (const float*)d_in[7];
    const float* Whh2 = (const float*)d_in[8];
    const float* bih2 = (const float*)d_in[9];
    const float* bhh2 = (const float*)d_in[10];
    const float* dWih = (const float*)d_in[11];
    const float* dWhh = (const float*)d_in[12];
    const float* dbih = (const float*)d_in[13];
    const float* dbhh = (const float*)d_in[14];
    const float* oW = (const float*)d_in[15];
    const float* ob = (const float*)d_in[16];
    float* out = (float*)d_out;

    char* ws = (char*)d_ws;
    size_t off = 0;
    auto alloc = [&](size_t bytes) -> char* {
        char* p = ws + off;
        off = (off + bytes + 255) & ~(size_t)255;
        return p;
    };
    const size_t HB = (size_t)BDIM * EDIM * 2;   // 2 MB bf16 state
    const size_t CB = (size_t)BDIM * EDIM * 4;   // 4 MB fp32 state
    const size_t WSZ = (size_t)262144 * 16;      // 4 MB swizzled split-W
    // zero-region (contiguous): h1_0, h2_0, c1, c2
    short* h1_0 = (short*)alloc(HB);
    short* h2_0 = (short*)alloc(HB);
    float* c1 = (float*)alloc(CB);
    float* c2 = (float*)alloc(CB);
    short* h1_1 = (short*)alloc(HB);
    short* h2_1 = (short*)alloc(HB);
    float* hf0 = (float*)alloc(CB);
    float* hf1 = (float*)alloc(CB);
    short* M1 = (short*)alloc((size_t)16384 * 16);
    short* sWhh1 = (short*)alloc(WSZ);
    short* sWih2 = (short*)alloc(WSZ);
    short* sWhh2 = (short*)alloc(WSZ);
    short* sdWhh = (short*)alloc(WSZ);
    short* sWsum = (short*)alloc(WSZ);
    float* bias1 = (float*)alloc(2048 * 4);
    float* bias2 = (float*)alloc(2048 * 4);
    float* biasd = (float*)alloc(2048 * 4);
    (void)ws_size; (void)in_sizes; (void)n_in; (void)out_size;

    zero_kernel<<<2048, 256, 0, stream>>>((unsigned int*)h1_0, (int)((2 * HB + 2 * CB) / 4));
    prep_bias<<<8, 256, 0, stream>>>(bih1, bhh1, Wih1, encb, bih2, bhh2, dbih, dbhh,
                                     bias1, bias2, biasd);
    swizzle_M1<<<512, 256, 0, stream>>>(Wih1, encW, M1);
    swizzle_w<<<1024, 256, 0, stream>>>(Whh1, nullptr, sWhh1);
    swizzle_w<<<1024, 256, 0, stream>>>(Wih2, nullptr, sWih2);
    swizzle_w<<<1024, 256, 0, stream>>>(Whh2, nullptr, sWhh2);
    swizzle_w<<<1024, 256, 0, stream>>>(dWhh, nullptr, sdWhh);
    swizzle_w<<<1024, 256, 0, stream>>>(dWih, dWhh, sWsum);

    dim3 grid(256), blk(512);
    short *h1p = h1_0, *h1n = h1_1, *h2p = h2_0, *h2n = h2_1;
    for (int t = 0; t < TSEQ; ++t) {
        lstm_cell_kernel<true, false><<<grid, blk, 0, stream>>>(
            x + t * POSE_D, M1, h1p, sWhh1, nullptr, nullptr,
            bias1, c1, h1n, nullptr);
        lstm_cell_kernel<false, true><<<grid, blk, 0, stream>>>(
            nullptr, nullptr, h1n, sWih2, h2p, sWhh2,
            bias2, c2, h2n, nullptr);
        short* t1 = h1p; h1p = h1n; h1n = t1;
        short* t2 = h2p; h2p = h2n; h2n = t2;
    }
    // decoder: bf16 h ping-pong reuses freed h1 buffers; fp32 copy for out_proj
    short* hd0 = h1_1;
    short* hd1 = h1_0;
    lstm_cell_kernel<false, false><<<grid, blk, 0, stream>>>(
        nullptr, nullptr, h2p, sdWhh, nullptr, nullptr,
        biasd, c2, hd0, hf0);
    out_proj<<<BDIM, 64, 0, stream>>>(hf0, oW, ob, out, 0);
    short *dp = hd0, *dn = hd1;
    float *fp = hf0, *fn = hf1;
    for (int f = 1; f < FUT; ++f) {
        lstm_cell_kernel<false, false><<<grid, blk, 0, stream>>>(
            nullptr, nullptr, dp, sWsum, nullptr, nullptr,
            biasd, c2, dn, fn);
        out_proj<<<BDIM, 64, 0, stream>>>(fn, oW, ob, out, f);
        short* tt = dp; dp = dn; dn = tt;
        float* tf = fp; fp = fn; fn = tf;
    }
}